// Round 11
// baseline (1414.467 us; speedup 1.0000x reference)
//
#include <hip/hip_runtime.h>
#include <hip/hip_bf16.h>
#include <cstdint>
#include <cmath>

typedef __bf16 bf16;
typedef __attribute__((ext_vector_type(8))) __bf16 bf16x8;
typedef __attribute__((ext_vector_type(4))) __bf16 bf16x4;
typedef __attribute__((ext_vector_type(4))) float f32x4;

// async global->LDS, 16B per lane, dest = wave-uniform base (+ lane*16 by HW)
__device__ __forceinline__ void gload_lds16(const void* g, void* l) {
  __builtin_amdgcn_global_load_lds((__attribute__((address_space(1))) void*)g,
                                   (__attribute__((address_space(3))) void*)l,
                                   16, 0, 0);
}

// ---------------------------------------------------------------------------
// Drift GEMM (round-5/7 proven, setprio removed): BM x 256 tile, BK=64,
// 8 waves (4M x 2N: wave = BM/4 rows x 128 cols), dbuf LDS, one __syncthreads
// per K-tile, full-tile prefetch front-loaded. C = A[M,K] @ Bt^T.
// LDS: buf*BUFS + {A:0,B:ASZ} + row*128 + (chunk^(row&7))*16 (conflict-free).
// EPI 1: f32 = acc+bias[col]+resid (Wo). EPI 2: f32 = acc+resid (W3).
// EPI 3: QKV fused RoPE + head reorder: q,k -> [h][s][128], v -> [h][128][s]
// EPI 4: FF fused SwiGLU on 16-interleaved W1/W2 -> g [s][11008]
// ---------------------------------------------------------------------------
template<int BM, int EPI>
__global__ __launch_bounds__(512, 2) void gemmd(
    const bf16* __restrict__ A, const bf16* __restrict__ Bt, void* __restrict__ Cv,
    const float* __restrict__ bias, const float* __restrict__ resid,
    const float* __restrict__ cosT, const float* __restrict__ sinT,
    bf16* __restrict__ q_out, bf16* __restrict__ k_out, bf16* __restrict__ v_out,
    int M, int N, int K, int gm) {
  extern __shared__ char lds[];
  constexpr int ASZ = BM * 128;
  constexpr int BUFS = ASZ + 32768;
  constexpr int MF = BM / 64;
  constexpr int LA = BM / 64;

  const int tid = threadIdx.x;
  const int wave = tid >> 6, lane = tid & 63;
  const int wr = wave >> 1, wc = wave & 1;   // 4M x 2N wave grid
  const int l15 = lane & 15, l4 = lane >> 4;
  const int qq = gridDim.x >> 3;
  const int wgid = (blockIdx.x & 7) * qq + (blockIdx.x >> 3);
  const int tm = wgid % gm, tn = wgid / gm;
  const long brow = (long)tm * BM, bcol = (long)tn * 256;
  const int NT = K >> 6;
  const bf16* Ab = A + brow * K;
  const bf16* Bb = Bt + bcol * K;

  f32x4 acc[MF][8];
  #pragma unroll
  for (int i = 0; i < MF; ++i)
    #pragma unroll
    for (int j = 0; j < 8; ++j) acc[i][j] = (f32x4){0.f, 0.f, 0.f, 0.f};

  bf16x8 a[MF][2], b[8][2];

  auto stage = [&](int T) {
    const long kofs = (long)T << 6;
    char* wb = lds + (T & 1) * BUFS;
    #pragma unroll
    for (int i = 0; i < LA; ++i) {
      const int slot = i * 512 + tid, r = slot >> 3, c0 = slot & 7;
      gload_lds16(Ab + (long)r * K + kofs + ((c0 ^ (r & 7)) << 3), wb + slot * 16);
    }
    #pragma unroll
    for (int i = 0; i < 4; ++i) {
      const int slot = i * 512 + tid, r = slot >> 3, c0 = slot & 7;
      gload_lds16(Bb + (long)r * K + kofs + ((c0 ^ (r & 7)) << 3), wb + ASZ + slot * 16);
    }
  };

  stage(0);
  __syncthreads();

  for (int g = 0; g < NT; ++g) {
    const int pg = (g & 1) * BUFS;
    if (g + 1 < NT) stage(g + 1);   // writes opposite buffer; fenced by barrier
    #pragma unroll
    for (int nf = 0; nf < 8; ++nf)
      #pragma unroll
      for (int ks = 0; ks < 2; ++ks) {
        const int r = wc * 128 + nf * 16 + l15;
        b[nf][ks] = *(const bf16x8*)(lds + pg + ASZ + r * 128 + (((ks * 4 + l4) ^ (r & 7)) << 4));
      }
    #pragma unroll
    for (int mf = 0; mf < MF; ++mf)
      #pragma unroll
      for (int ks = 0; ks < 2; ++ks) {
        const int r = wr * (BM / 4) + mf * 16 + l15;
        a[mf][ks] = *(const bf16x8*)(lds + pg + r * 128 + (((ks * 4 + l4) ^ (r & 7)) << 4));
      }
    #pragma unroll
    for (int ks = 0; ks < 2; ++ks)
      #pragma unroll
      for (int mf = 0; mf < MF; ++mf)
        #pragma unroll
        for (int nf = 0; nf < 8; ++nf)
          acc[mf][nf] = __builtin_amdgcn_mfma_f32_16x16x32_bf16(
              a[mf][ks], b[nf][ks], acc[mf][nf], 0, 0, 0);
    __syncthreads();
  }

  if (EPI == 1 || EPI == 2) {
    #pragma unroll
    for (int mf = 0; mf < MF; ++mf) {
      const long row0 = brow + wr * (BM / 4) + mf * 16 + l4 * 4;
      #pragma unroll
      for (int nf = 0; nf < 8; ++nf) {
        const long col = bcol + wc * 128 + nf * 16 + l15;
        #pragma unroll
        for (int rj = 0; rj < 4; ++rj) {
          const long idx = (row0 + rj) * N + col;
          const float v = acc[mf][nf][rj];
          if (EPI == 1) ((float*)Cv)[idx] = v + bias[col] + resid[idx];
          else          ((float*)Cv)[idx] = v + resid[idx];
        }
      }
    }
  } else if (EPI == 3) {
    const int region = (int)(bcol >> 12);           // 0=Q, 1=K, 2=V
    const int hc = (int)(bcol & 4095) + wc * 128;
    const int h = hc >> 7;
    if (region < 2) {
      bf16* dh = (region == 0 ? q_out : k_out) + (long)h * 2048 * 128;
      #pragma unroll
      for (int mf = 0; mf < MF; ++mf) {
        #pragma unroll
        for (int rj = 0; rj < 4; ++rj) {
          const int s = (int)brow + wr * (BM / 4) + mf * 16 + l4 * 4 + rj;
          const float* cr = cosT + s * 64;
          const float* sr = sinT + s * 64;
          #pragma unroll
          for (int nfp = 0; nfp < 4; ++nfp) {
            const int d = nfp * 16 + l15;
            const float c = cr[d], sn = sr[d];
            const float x1 = acc[mf][nfp][rj], x2 = acc[mf][nfp + 4][rj];
            dh[(long)s * 128 + d]      = (bf16)(x1 * c - x2 * sn);
            dh[(long)s * 128 + d + 64] = (bf16)(x2 * c + x1 * sn);
          }
        }
      }
    } else {
      bf16* dh = v_out + (long)h * 128 * 2048;
      #pragma unroll
      for (int mf = 0; mf < MF; ++mf) {
        const int s0 = (int)brow + wr * (BM / 4) + mf * 16 + l4 * 4;
        #pragma unroll
        for (int nf = 0; nf < 8; ++nf) {
          const int d = nf * 16 + l15;
          bf16x4 v;
          #pragma unroll
          for (int rj = 0; rj < 4; ++rj) v[rj] = (bf16)acc[mf][nf][rj];
          *(bf16x4*)(dh + (long)d * 2048 + s0) = v;
        }
      }
    }
  } else if (EPI == 4) {  // fused SwiGLU on 16-interleaved W12 -> g [s][11008]
    #pragma unroll
    for (int mf = 0; mf < MF; ++mf) {
      #pragma unroll
      for (int rj = 0; rj < 4; ++rj) {
        const int s = (int)brow + wr * (BM / 4) + mf * 16 + l4 * 4 + rj;
        bf16* gr = (bf16*)Cv + (long)s * 11008;
        #pragma unroll
        for (int nfp = 0; nfp < 4; ++nfp) {
          const int col = (int)bcol + wc * 128 + nfp * 32 + l15;
          const int jj = ((col >> 5) << 4) + l15;
          const float x1 = acc[mf][2 * nfp][rj], x2 = acc[mf][2 * nfp + 1][rj];
          const float sg = x1 / (1.f + __expf(-x1));
          gr[jj] = (bf16)(sg * x2);
        }
      }
    }
  }
}

// ---------------------------------------------------------------------------
// Merged prep kernel: all weight transposes (f32->bf16) + RoPE tables in ONE
// launch. Segments by blockIdx.x:
//  [0,4096)      Wq -> WqkvT           (4096x4096, plain)
//  [4096,8192)   Wk -> WqkvT+16M       (plain)
//  [8192,12288)  Wv -> WqkvT+32M       (plain)
//  [12288,16384) Wo -> WoT             (plain)
//  [16384,27392) W1 -> W12T            (4096x11008, interleave off=0)
//  [27392,38400) W2 -> W12T            (interleave off=16)
//  [38400,49408) W3 -> W3T             (11008x4096, plain)
//  [49408,49920) rope cos/sin tables   (2048x64)
// ---------------------------------------------------------------------------
__device__ __forceinline__ void trans64(
    const float* __restrict__ in, bf16* __restrict__ out,
    int R, int C, int bx, int by, int ilv, int off) {
  __shared__ float t[64][65];
  const int lr = threadIdx.x >> 4;
  const int lc4 = (threadIdx.x & 15) * 4;
  #pragma unroll
  for (int i = 0; i < 4; ++i) {
    const int r = lr + i * 16;
    const float4 v = *(const float4*)(in + (long)(by * 64 + r) * C + bx * 64 + lc4);
    t[r][lc4] = v.x; t[r][lc4 + 1] = v.y; t[r][lc4 + 2] = v.z; t[r][lc4 + 3] = v.w;
  }
  __syncthreads();
  const int oc = threadIdx.x >> 4;
  const int or4 = (threadIdx.x & 15) * 4;
  #pragma unroll
  for (int i = 0; i < 4; ++i) {
    const int c = oc + i * 16;
    const int j = bx * 64 + c;
    const int rdst = ilv ? (((j >> 4) << 5) + off + (j & 15)) : j;
    bf16x4 v;
    #pragma unroll
    for (int k = 0; k < 4; ++k) v[k] = (bf16)t[or4 + k][c];
    *(bf16x4*)(out + (long)rdst * R + by * 64 + or4) = v;
  }
}

__global__ __launch_bounds__(256) void prep_kernel(
    const float* __restrict__ Wq, const float* __restrict__ Wk,
    const float* __restrict__ Wv, const float* __restrict__ Wo,
    const float* __restrict__ W1, const float* __restrict__ W2,
    const float* __restrict__ W3,
    bf16* __restrict__ WqkvT, bf16* __restrict__ WoT,
    bf16* __restrict__ W12T, bf16* __restrict__ W3T,
    float* __restrict__ cosT, float* __restrict__ sinT) {
  const int bid = blockIdx.x;
  if (bid < 16384) {
    const int seg = bid >> 12, idx = bid & 4095;
    const float* in = (seg == 0 ? Wq : seg == 1 ? Wk : seg == 2 ? Wv : Wo);
    bf16* out = (seg == 3 ? WoT : WqkvT + (long)seg * 4096 * 4096);
    trans64(in, out, 4096, 4096, idx & 63, idx >> 6, 0, 0);
  } else if (bid < 38400) {
    const int idx = bid - 16384;
    const int seg = idx / 11008, li = idx % 11008;
    trans64(seg ? W2 : W1, W12T, 4096, 11008, li % 172, li / 172, 1, seg * 16);
  } else if (bid < 49408) {
    const int idx = bid - 38400;
    trans64(W3, W3T, 11008, 4096, idx & 63, idx >> 6, 0, 0);
  } else {
    const int gidx = (bid - 49408) * 256 + threadIdx.x;
    const int i = gidx & 63, s = gidx >> 6;
    const float inv = powf(10000.f, -(float)i / 64.f);
    const float ang = (float)s * inv;
    cosT[gidx] = cosf(ang);
    sinT[gidx] = sinf(ang);
  }
}

// ---------------------------------------------------------------------------
// RMSNorm: one block per row of [2048][4096] f32 -> bf16
// ---------------------------------------------------------------------------
__global__ __launch_bounds__(256) void rmsnorm_kernel(
    const float* __restrict__ X, const float* __restrict__ gamma,
    bf16* __restrict__ out, int D) {
  const int row = blockIdx.x;
  const float* xr = X + (long)row * D;
  float ss = 0.f;
  for (int i = threadIdx.x * 4; i < D; i += 1024) {
    float4 v = *(const float4*)(xr + i);
    ss += v.x * v.x + v.y * v.y + v.z * v.z + v.w * v.w;
  }
  #pragma unroll
  for (int off = 32; off; off >>= 1) ss += __shfl_down(ss, off, 64);
  __shared__ float wsum[4];
  if ((threadIdx.x & 63) == 0) wsum[threadIdx.x >> 6] = ss;
  __syncthreads();
  const float tot = wsum[0] + wsum[1] + wsum[2] + wsum[3];
  const float scale = rsqrtf(1e-7f + tot / (float)D);
  bf16* orow = out + (long)row * D;
  for (int i = threadIdx.x * 4; i < D; i += 1024) {
    float4 v = *(const float4*)(xr + i);
    float4 g = *(const float4*)(gamma + i);
    orow[i]     = (bf16)(v.x * scale * g.x);
    orow[i + 1] = (bf16)(v.y * scale * g.y);
    orow[i + 2] = (bf16)(v.z * scale * g.z);
    orow[i + 3] = (bf16)(v.w * scale * g.w);
  }
}

// ---------------------------------------------------------------------------
// Flash attention, causal. Block=(qb,head), 4 waves x 16 q-rows. K/V dbuf.
// ---------------------------------------------------------------------------
__global__ __launch_bounds__(256) void attn_kernel(
    const bf16* __restrict__ qh, const bf16* __restrict__ kh,
    const bf16* __restrict__ vt, bf16* __restrict__ outb) {
  constexpr int S = 2048;
  const int qb = blockIdx.x, head = blockIdx.y;
  const int tid = threadIdx.x, wave = tid >> 6, lane = tid & 63;
  __shared__ bf16 Ks[2][64 * 128];
  __shared__ bf16 Vs[2][128 * 64];
  __shared__ bf16 Plds[4][16 * 64];
  const bf16* qhh = qh + (long)head * S * 128;
  const bf16* khh = kh + (long)head * S * 128;
  const bf16* vth = vt + (long)head * 128 * S;

  const int l15 = lane & 15, l4 = lane >> 4;
  const int qrow = qb * 64 + wave * 16 + l15;
  bf16x8 qf[4];
  #pragma unroll
  for (int kf = 0; kf < 4; ++kf)
    qf[kf] = *(const bf16x8*)(qhh + (long)qrow * 128 + kf * 32 + l4 * 8);

  auto stageKV = [&](int tb, int buf) {
    #pragma unroll
    for (int i = 0; i < 4; ++i) {
      const int c = wave + 4 * i;
      gload_lds16(khh + (long)(tb * 64 + c * 4 + l4) * 128 + l15 * 8, Ks[buf] + c * 512);
      gload_lds16(vth + (long)(c * 8 + (lane >> 3)) * S + tb * 64 + (lane & 7) * 8, Vs[buf] + c * 512);
    }
  };

  float m_r[4], l_r[4];
  #pragma unroll
  for (int r = 0; r < 4; ++r) { m_r[r] = -INFINITY; l_r[r] = 0.f; }
  f32x4 oacc[8] = {};
  const float scale = 0.08838834764831845f;

  stageKV(0, 0);
  __syncthreads();

  for (int tb = 0; tb <= qb; ++tb) {
    const int buf = tb & 1;
    if (tb < qb) stageKV(tb + 1, buf ^ 1);

    f32x4 sf[4];
    #pragma unroll
    for (int ft = 0; ft < 4; ++ft) {
      f32x4 acn = {};
      #pragma unroll
      for (int kf = 0; kf < 4; ++kf) {
        bf16x8 kfr = *(const bf16x8*)(Ks[buf] + (ft * 16 + l15) * 128 + kf * 32 + l4 * 8);
        acn = __builtin_amdgcn_mfma_f32_16x16x32_bf16(qf[kf], kfr, acn, 0, 0, 0);
      }
      #pragma unroll
      for (int r = 0; r < 4; ++r) sf[ft][r] = acn[r] * scale;
    }
    if (tb == qb) {
      #pragma unroll
      for (int ft = 0; ft < 4; ++ft) {
        const int t_l = ft * 16 + l15;
        #pragma unroll
        for (int r = 0; r < 4; ++r)
          if (t_l > wave * 16 + l4 * 4 + r) sf[ft][r] = -INFINITY;
      }
    }
    float scl[4];
    #pragma unroll
    for (int r = 0; r < 4; ++r) {
      float mx = fmaxf(fmaxf(sf[0][r], sf[1][r]), fmaxf(sf[2][r], sf[3][r]));
      mx = fmaxf(mx, __shfl_xor(mx, 1, 64));
      mx = fmaxf(mx, __shfl_xor(mx, 2, 64));
      mx = fmaxf(mx, __shfl_xor(mx, 4, 64));
      mx = fmaxf(mx, __shfl_xor(mx, 8, 64));
      const float mnew = fmaxf(m_r[r], mx);
      scl[r] = __expf(m_r[r] - mnew);
      m_r[r] = mnew;
      float rs = 0.f;
      #pragma unroll
      for (int ft = 0; ft < 4; ++ft) {
        const float pexp = __expf(sf[ft][r] - mnew);
        sf[ft][r] = pexp;
        rs += pexp;
      }
      rs += __shfl_xor(rs, 1, 64);
      rs += __shfl_xor(rs, 2, 64);
      rs += __shfl_xor(rs, 4, 64);
      rs += __shfl_xor(rs, 8, 64);
      l_r[r] = l_r[r] * scl[r] + rs;
    }
    #pragma unroll
    for (int ft = 0; ft < 4; ++ft)
      #pragma unroll
      for (int r = 0; r < 4; ++r)
        Plds[wave][(l4 * 4 + r) * 64 + ft * 16 + l15] = (bf16)sf[ft][r];
    #pragma unroll
    for (int fd = 0; fd < 8; ++fd)
      #pragma unroll
      for (int r = 0; r < 4; ++r) oacc[fd][r] *= scl[r];
    #pragma unroll
    for (int fd = 0; fd < 8; ++fd) {
      #pragma unroll
      for (int kt = 0; kt < 2; ++kt) {
        bf16x8 pa = *(const bf16x8*)(&Plds[wave][l15 * 64 + kt * 32 + l4 * 8]);
        bf16x8 vb = *(const bf16x8*)(Vs[buf] + (fd * 16 + l15) * 64 + kt * 32 + l4 * 8);
        oacc[fd] = __builtin_amdgcn_mfma_f32_16x16x32_bf16(pa, vb, oacc[fd], 0, 0, 0);
      }
    }
    __syncthreads();
  }
  #pragma unroll
  for (int fd = 0; fd < 8; ++fd) {
    #pragma unroll
    for (int r = 0; r < 4; ++r) {
      const long row = qb * 64 + wave * 16 + l4 * 4 + r;
      outb[row * 4096 + head * 128 + fd * 16 + l15] = (bf16)(oacc[fd][r] / l_r[r]);
    }
  }
}

// ---------------------------------------------------------------------------
extern "C" void kernel_launch(void* const* d_in, const int* in_sizes, int n_in,
                              void* d_out, int out_size, void* d_ws, size_t ws_size,
                              hipStream_t stream) {
  const float* X  = (const float*)d_in[0];
  const float* Wq = (const float*)d_in[1];
  const float* Wk = (const float*)d_in[2];
  const float* Wv = (const float*)d_in[3];
  const float* Wo = (const float*)d_in[4];
  const float* bo = (const float*)d_in[5];
  const float* g1 = (const float*)d_in[6];
  const float* g2 = (const float*)d_in[7];
  const float* W1 = (const float*)d_in[8];
  const float* W2 = (const float*)d_in[9];
  const float* W3 = (const float*)d_in[10];
  float* out = (float*)d_out;

  hipFuncSetAttribute((const void*)gemmd<256, 3>, hipFuncAttributeMaxDynamicSharedMemorySize, 131072);
  hipFuncSetAttribute((const void*)gemmd<256, 4>, hipFuncAttributeMaxDynamicSharedMemorySize, 131072);
  hipFuncSetAttribute((const void*)gemmd<128, 1>, hipFuncAttributeMaxDynamicSharedMemorySize, 98304);
  hipFuncSetAttribute((const void*)gemmd<128, 2>, hipFuncAttributeMaxDynamicSharedMemorySize, 98304);

  char* p = (char*)d_ws;
  auto alloc = [&](size_t bytes) {
    char* r = p;
    p += (bytes + 255) & ~(size_t)255;
    return r;
  };
  float* cosT = (float*)alloc(2048 * 64 * 4);
  float* sinT = (float*)alloc(2048 * 64 * 4);
  bf16* WqkvT = (bf16*)alloc(12288L * 4096 * 2);   // [12288][4096]; later g
  bf16* WoT  = (bf16*)alloc(4096L * 4096 * 2);
  bf16* W12T = (bf16*)alloc(22016L * 4096 * 2);    // interleaved [22016][4096]
  bf16* W3T  = (bf16*)alloc(4096L * 11008 * 2);
  bf16* qhB  = (bf16*)alloc(2048L * 4096 * 2);     // [32][2048][128]
  bf16* khB  = (bf16*)alloc(2048L * 4096 * 2);
  bf16* vtB  = (bf16*)alloc(2048L * 4096 * 2);     // [32][128][2048]
  bf16* hbuf = (bf16*)alloc(2048L * 4096 * 2);     // h, then attnb
  bf16* h2   = (bf16*)alloc(2048L * 4096 * 2);
  float* X2  = (float*)alloc(2048L * 4096 * 4);

  bf16* gsw = (bf16*)WqkvT;   // g [2048][11008] (WqkvT dead after QKV GEMM)
  bf16* attnb = hbuf;

  // all weight transposes + rope tables in one launch
  prep_kernel<<<49920, 256, 0, stream>>>(Wq, Wk, Wv, Wo, W1, W2, W3,
                                         WqkvT, WoT, W12T, W3T, cosT, sinT);

  rmsnorm_kernel<<<2048, 256, 0, stream>>>(X, g1, hbuf, 4096);

  // q,k,v = rope/reorder(h @ [Wq|Wk|Wv])  — drift-256, fused epilogue
  gemmd<256, 3><<<384, 512, 131072, stream>>>(hbuf, WqkvT, nullptr, nullptr, nullptr,
                                              cosT, sinT, qhB, khB, vtB,
                                              2048, 12288, 4096, 8);

  attn_kernel<<<dim3(32, 32), 256, 0, stream>>>(qhB, khB, vtB, attnb);

  // X2 = attn @ Wo + bo + X   (drift-128)
  gemmd<128, 1><<<256, 512, 98304, stream>>>(attnb, WoT, X2, bo, X,
                                             nullptr, nullptr, nullptr, nullptr, nullptr,
                                             2048, 4096, 4096, 16);

  rmsnorm_kernel<<<2048, 256, 0, stream>>>(X2, g2, h2, 4096);

  // g = silu(h2@W1) * (h2@W2)  — drift-256, fused SwiGLU epilogue
  gemmd<256, 4><<<688, 512, 131072, stream>>>(h2, W12T, gsw, nullptr, nullptr,
                                              nullptr, nullptr, nullptr, nullptr, nullptr,
                                              2048, 22016, 4096, 8);

  // out = g @ W3 + X2   (drift-128)
  gemmd<128, 2><<<256, 512, 98304, stream>>>(gsw, W3T, out, nullptr, X2,
                                             nullptr, nullptr, nullptr, nullptr, nullptr,
                                             2048, 4096, 11008, 16);
}

// Round 12
// 1307.149 us; speedup vs baseline: 1.0821x; 1.0821x over previous
//
#include <hip/hip_runtime.h>
#include <hip/hip_bf16.h>
#include <cstdint>
#include <cmath>

typedef __bf16 bf16;
typedef __attribute__((ext_vector_type(8))) __bf16 bf16x8;
typedef __attribute__((ext_vector_type(4))) __bf16 bf16x4;
typedef __attribute__((ext_vector_type(4))) float f32x4;

// async global->LDS, 16B per lane, dest = wave-uniform base (+ lane*16 by HW)
__device__ __forceinline__ void gload_lds16(const void* g, void* l) {
  __builtin_amdgcn_global_load_lds((__attribute__((address_space(1))) void*)g,
                                   (__attribute__((address_space(3))) void*)l,
                                   16, 0, 0);
}

// ---------------------------------------------------------------------------
// Drift GEMM (R11 best) + per-ks read->MFMA interleave: BM x 256 tile, BK=64,
// 8 waves (4M x 2N: wave = BM/4 rows x 128 cols), dbuf LDS, one __syncthreads
// per K-tile, full-tile prefetch front-loaded. Inner loop now alternates
// {12 ds_read, 32 MFMA} per ks so the 2 waves/SIMD anti-phase (port || MFMA).
// C = A[M,K] @ Bt^T.
// LDS: buf*BUFS + {A:0,B:ASZ} + row*128 + (chunk^(row&7))*16 (conflict-free).
// EPI 1: f32 = acc+bias[col]+resid (Wo). EPI 2: f32 = acc+resid (W3).
// EPI 3: QKV fused RoPE + head reorder: q,k -> [h][s][128], v -> [h][128][s]
// EPI 4: FF fused SwiGLU on 16-interleaved W1/W2 -> g [s][11008]
// ---------------------------------------------------------------------------
template<int BM, int EPI>
__global__ __launch_bounds__(512, 2) void gemmd(
    const bf16* __restrict__ A, const bf16* __restrict__ Bt, void* __restrict__ Cv,
    const float* __restrict__ bias, const float* __restrict__ resid,
    const float* __restrict__ cosT, const float* __restrict__ sinT,
    bf16* __restrict__ q_out, bf16* __restrict__ k_out, bf16* __restrict__ v_out,
    int M, int N, int K, int gm) {
  extern __shared__ char lds[];
  constexpr int ASZ = BM * 128;
  constexpr int BUFS = ASZ + 32768;
  constexpr int MF = BM / 64;
  constexpr int LA = BM / 64;

  const int tid = threadIdx.x;
  const int wave = tid >> 6, lane = tid & 63;
  const int wr = wave >> 1, wc = wave & 1;   // 4M x 2N wave grid
  const int l15 = lane & 15, l4 = lane >> 4;
  const int qq = gridDim.x >> 3;
  const int wgid = (blockIdx.x & 7) * qq + (blockIdx.x >> 3);
  const int tm = wgid % gm, tn = wgid / gm;
  const long brow = (long)tm * BM, bcol = (long)tn * 256;
  const int NT = K >> 6;
  const bf16* Ab = A + brow * K;
  const bf16* Bb = Bt + bcol * K;

  f32x4 acc[MF][8];
  #pragma unroll
  for (int i = 0; i < MF; ++i)
    #pragma unroll
    for (int j = 0; j < 8; ++j) acc[i][j] = (f32x4){0.f, 0.f, 0.f, 0.f};

  bf16x8 a[MF], b[8];

  auto stage = [&](int T) {
    const long kofs = (long)T << 6;
    char* wb = lds + (T & 1) * BUFS;
    #pragma unroll
    for (int i = 0; i < LA; ++i) {
      const int slot = i * 512 + tid, r = slot >> 3, c0 = slot & 7;
      gload_lds16(Ab + (long)r * K + kofs + ((c0 ^ (r & 7)) << 3), wb + slot * 16);
    }
    #pragma unroll
    for (int i = 0; i < 4; ++i) {
      const int slot = i * 512 + tid, r = slot >> 3, c0 = slot & 7;
      gload_lds16(Bb + (long)r * K + kofs + ((c0 ^ (r & 7)) << 3), wb + ASZ + slot * 16);
    }
  };

  stage(0);
  __syncthreads();

  for (int g = 0; g < NT; ++g) {
    const int pg = (g & 1) * BUFS;
    if (g + 1 < NT) stage(g + 1);   // writes opposite buffer; fenced by barrier
    #pragma unroll
    for (int ks = 0; ks < 2; ++ks) {
      #pragma unroll
      for (int nf = 0; nf < 8; ++nf) {
        const int r = wc * 128 + nf * 16 + l15;
        b[nf] = *(const bf16x8*)(lds + pg + ASZ + r * 128 + (((ks * 4 + l4) ^ (r & 7)) << 4));
      }
      #pragma unroll
      for (int mf = 0; mf < MF; ++mf) {
        const int r = wr * (BM / 4) + mf * 16 + l15;
        a[mf] = *(const bf16x8*)(lds + pg + r * 128 + (((ks * 4 + l4) ^ (r & 7)) << 4));
      }
      #pragma unroll
      for (int mf = 0; mf < MF; ++mf)
        #pragma unroll
        for (int nf = 0; nf < 8; ++nf)
          acc[mf][nf] = __builtin_amdgcn_mfma_f32_16x16x32_bf16(
              a[mf], b[nf], acc[mf][nf], 0, 0, 0);
    }
    __syncthreads();
  }

  if (EPI == 1 || EPI == 2) {
    #pragma unroll
    for (int mf = 0; mf < MF; ++mf) {
      const long row0 = brow + wr * (BM / 4) + mf * 16 + l4 * 4;
      #pragma unroll
      for (int nf = 0; nf < 8; ++nf) {
        const long col = bcol + wc * 128 + nf * 16 + l15;
        #pragma unroll
        for (int rj = 0; rj < 4; ++rj) {
          const long idx = (row0 + rj) * N + col;
          const float v = acc[mf][nf][rj];
          if (EPI == 1) ((float*)Cv)[idx] = v + bias[col] + resid[idx];
          else          ((float*)Cv)[idx] = v + resid[idx];
        }
      }
    }
  } else if (EPI == 3) {
    const int region = (int)(bcol >> 12);           // 0=Q, 1=K, 2=V
    const int hc = (int)(bcol & 4095) + wc * 128;
    const int h = hc >> 7;
    if (region < 2) {
      bf16* dh = (region == 0 ? q_out : k_out) + (long)h * 2048 * 128;
      #pragma unroll
      for (int mf = 0; mf < MF; ++mf) {
        #pragma unroll
        for (int rj = 0; rj < 4; ++rj) {
          const int s = (int)brow + wr * (BM / 4) + mf * 16 + l4 * 4 + rj;
          const float* cr = cosT + s * 64;
          const float* sr = sinT + s * 64;
          #pragma unroll
          for (int nfp = 0; nfp < 4; ++nfp) {
            const int d = nfp * 16 + l15;
            const float c = cr[d], sn = sr[d];
            const float x1 = acc[mf][nfp][rj], x2 = acc[mf][nfp + 4][rj];
            dh[(long)s * 128 + d]      = (bf16)(x1 * c - x2 * sn);
            dh[(long)s * 128 + d + 64] = (bf16)(x2 * c + x1 * sn);
          }
        }
      }
    } else {
      bf16* dh = v_out + (long)h * 128 * 2048;
      #pragma unroll
      for (int mf = 0; mf < MF; ++mf) {
        const int s0 = (int)brow + wr * (BM / 4) + mf * 16 + l4 * 4;
        #pragma unroll
        for (int nf = 0; nf < 8; ++nf) {
          const int d = nf * 16 + l15;
          bf16x4 v;
          #pragma unroll
          for (int rj = 0; rj < 4; ++rj) v[rj] = (bf16)acc[mf][nf][rj];
          *(bf16x4*)(dh + (long)d * 2048 + s0) = v;
        }
      }
    }
  } else if (EPI == 4) {
    #pragma unroll
    for (int mf = 0; mf < MF; ++mf) {
      #pragma unroll
      for (int rj = 0; rj < 4; ++rj) {
        const int s = (int)brow + wr * (BM / 4) + mf * 16 + l4 * 4 + rj;
        bf16* gr = (bf16*)Cv + (long)s * 11008;
        #pragma unroll
        for (int nfp = 0; nfp < 4; ++nfp) {
          const int col = (int)bcol + wc * 128 + nfp * 32 + l15;
          const int jj = ((col >> 5) << 4) + l15;
          const float x1 = acc[mf][2 * nfp][rj], x2 = acc[mf][2 * nfp + 1][rj];
          const float sg = x1 / (1.f + __expf(-x1));
          gr[jj] = (bf16)(sg * x2);
        }
      }
    }
  }
}

// ---------------------------------------------------------------------------
// Merged prep kernel (unchanged from R11)
// ---------------------------------------------------------------------------
__device__ __forceinline__ void trans64(
    const float* __restrict__ in, bf16* __restrict__ out,
    int R, int C, int bx, int by, int ilv, int off) {
  __shared__ float t[64][65];
  const int lr = threadIdx.x >> 4;
  const int lc4 = (threadIdx.x & 15) * 4;
  #pragma unroll
  for (int i = 0; i < 4; ++i) {
    const int r = lr + i * 16;
    const float4 v = *(const float4*)(in + (long)(by * 64 + r) * C + bx * 64 + lc4);
    t[r][lc4] = v.x; t[r][lc4 + 1] = v.y; t[r][lc4 + 2] = v.z; t[r][lc4 + 3] = v.w;
  }
  __syncthreads();
  const int oc = threadIdx.x >> 4;
  const int or4 = (threadIdx.x & 15) * 4;
  #pragma unroll
  for (int i = 0; i < 4; ++i) {
    const int c = oc + i * 16;
    const int j = bx * 64 + c;
    const int rdst = ilv ? (((j >> 4) << 5) + off + (j & 15)) : j;
    bf16x4 v;
    #pragma unroll
    for (int k = 0; k < 4; ++k) v[k] = (bf16)t[or4 + k][c];
    *(bf16x4*)(out + (long)rdst * R + by * 64 + or4) = v;
  }
}

__global__ __launch_bounds__(256) void prep_kernel(
    const float* __restrict__ Wq, const float* __restrict__ Wk,
    const float* __restrict__ Wv, const float* __restrict__ Wo,
    const float* __restrict__ W1, const float* __restrict__ W2,
    const float* __restrict__ W3,
    bf16* __restrict__ WqkvT, bf16* __restrict__ WoT,
    bf16* __restrict__ W12T, bf16* __restrict__ W3T,
    float* __restrict__ cosT, float* __restrict__ sinT) {
  const int bid = blockIdx.x;
  if (bid < 16384) {
    const int seg = bid >> 12, idx = bid & 4095;
    const float* in = (seg == 0 ? Wq : seg == 1 ? Wk : seg == 2 ? Wv : Wo);
    bf16* out = (seg == 3 ? WoT : WqkvT + (long)seg * 4096 * 4096);
    trans64(in, out, 4096, 4096, idx & 63, idx >> 6, 0, 0);
  } else if (bid < 38400) {
    const int idx = bid - 16384;
    const int seg = idx / 11008, li = idx % 11008;
    trans64(seg ? W2 : W1, W12T, 4096, 11008, li % 172, li / 172, 1, seg * 16);
  } else if (bid < 49408) {
    const int idx = bid - 38400;
    trans64(W3, W3T, 11008, 4096, idx & 63, idx >> 6, 0, 0);
  } else {
    const int gidx = (bid - 49408) * 256 + threadIdx.x;
    const int i = gidx & 63, s = gidx >> 6;
    const float inv = powf(10000.f, -(float)i / 64.f);
    const float ang = (float)s * inv;
    cosT[gidx] = cosf(ang);
    sinT[gidx] = sinf(ang);
  }
}

// ---------------------------------------------------------------------------
// RMSNorm: one block per row of [2048][4096] f32 -> bf16
// ---------------------------------------------------------------------------
__global__ __launch_bounds__(256) void rmsnorm_kernel(
    const float* __restrict__ X, const float* __restrict__ gamma,
    bf16* __restrict__ out, int D) {
  const int row = blockIdx.x;
  const float* xr = X + (long)row * D;
  float ss = 0.f;
  for (int i = threadIdx.x * 4; i < D; i += 1024) {
    float4 v = *(const float4*)(xr + i);
    ss += v.x * v.x + v.y * v.y + v.z * v.z + v.w * v.w;
  }
  #pragma unroll
  for (int off = 32; off; off >>= 1) ss += __shfl_down(ss, off, 64);
  __shared__ float wsum[4];
  if ((threadIdx.x & 63) == 0) wsum[threadIdx.x >> 6] = ss;
  __syncthreads();
  const float tot = wsum[0] + wsum[1] + wsum[2] + wsum[3];
  const float scale = rsqrtf(1e-7f + tot / (float)D);
  bf16* orow = out + (long)row * D;
  for (int i = threadIdx.x * 4; i < D; i += 1024) {
    float4 v = *(const float4*)(xr + i);
    float4 g = *(const float4*)(gamma + i);
    orow[i]     = (bf16)(v.x * scale * g.x);
    orow[i + 1] = (bf16)(v.y * scale * g.y);
    orow[i + 2] = (bf16)(v.z * scale * g.z);
    orow[i + 3] = (bf16)(v.w * scale * g.w);
  }
}

// ---------------------------------------------------------------------------
// Flash attention, causal. Block=(qb,head), 4 waves x 16 q-rows. K/V dbuf.
// LDS conflict fix (rule #21 both-sides): per-lane SOURCE slot permutation at
// gload_lds time produces XOR-swizzled LDS; reads apply the same XOR.
//   Ks [64][128]e (16 slots/row): slot' = slot ^ (row&15)  -> 4-way
//   Vs [128][64]e (8 slots/row):  slot' = slot ^ (row&7)   -> 8-way
//   Plds [16][64]e (8 slots/row): slot' = slot ^ (q&7)     -> 8-way
// ---------------------------------------------------------------------------
__global__ __launch_bounds__(256) void attn_kernel(
    const bf16* __restrict__ qh, const bf16* __restrict__ kh,
    const bf16* __restrict__ vt, bf16* __restrict__ outb) {
  constexpr int S = 2048;
  const int qb = blockIdx.x, head = blockIdx.y;
  const int tid = threadIdx.x, wave = tid >> 6, lane = tid & 63;
  __shared__ bf16 Ks[2][64 * 128];
  __shared__ bf16 Vs[2][128 * 64];
  __shared__ bf16 Plds[4][16 * 64];
  const bf16* qhh = qh + (long)head * S * 128;
  const bf16* khh = kh + (long)head * S * 128;
  const bf16* vth = vt + (long)head * 128 * S;

  const int l15 = lane & 15, l4 = lane >> 4;
  const int qrow = qb * 64 + wave * 16 + l15;
  bf16x8 qf[4];
  #pragma unroll
  for (int kf = 0; kf < 4; ++kf)
    qf[kf] = *(const bf16x8*)(qhh + (long)qrow * 128 + kf * 32 + l4 * 8);

  auto stageKV = [&](int tb, int buf) {
    #pragma unroll
    for (int i = 0; i < 4; ++i) {
      const int c = wave + 4 * i;
      // K: row = c*4 + l4 (rows of 128 elems, 16 slots); lane writes phys
      // slot l15 -> load logical slot l15 ^ (row&15)
      const int krlow = (c & 3) * 4 + l4;
      gload_lds16(khh + (long)(tb * 64 + c * 4 + l4) * 128 + ((l15 ^ krlow) * 8),
                  Ks[buf] + c * 512);
      // V: row = c*8 + (lane>>3) (rows of 64 elems, 8 slots); phys slot lane&7
      // -> load logical slot (lane&7) ^ (row&7)
      gload_lds16(vth + (long)(c * 8 + (lane >> 3)) * S + tb * 64 +
                      (((lane & 7) ^ (lane >> 3)) * 8),
                  Vs[buf] + c * 512);
    }
  };

  float m_r[4], l_r[4];
  #pragma unroll
  for (int r = 0; r < 4; ++r) { m_r[r] = -INFINITY; l_r[r] = 0.f; }
  f32x4 oacc[8] = {};
  const float scale = 0.08838834764831845f;

  stageKV(0, 0);
  __syncthreads();

  for (int tb = 0; tb <= qb; ++tb) {
    const int buf = tb & 1;
    if (tb < qb) stageKV(tb + 1, buf ^ 1);

    f32x4 sf[4];
    #pragma unroll
    for (int ft = 0; ft < 4; ++ft) {
      f32x4 acn = {};
      #pragma unroll
      for (int kf = 0; kf < 4; ++kf) {
        // row = ft*16+l15, logical slot kf*4+l4 -> phys slot ^ (row&15)=l15
        bf16x8 kfr = *(const bf16x8*)(Ks[buf] + (ft * 16 + l15) * 128 +
                                      (((kf * 4 + l4) ^ l15) * 8));
        acn = __builtin_amdgcn_mfma_f32_16x16x32_bf16(qf[kf], kfr, acn, 0, 0, 0);
      }
      #pragma unroll
      for (int r = 0; r < 4; ++r) sf[ft][r] = acn[r] * scale;
    }
    if (tb == qb) {
      #pragma unroll
      for (int ft = 0; ft < 4; ++ft) {
        const int t_l = ft * 16 + l15;
        #pragma unroll
        for (int r = 0; r < 4; ++r)
          if (t_l > wave * 16 + l4 * 4 + r) sf[ft][r] = -INFINITY;
      }
    }
    float scl[4];
    #pragma unroll
    for (int r = 0; r < 4; ++r) {
      float mx = fmaxf(fmaxf(sf[0][r], sf[1][r]), fmaxf(sf[2][r], sf[3][r]));
      mx = fmaxf(mx, __shfl_xor(mx, 1, 64));
      mx = fmaxf(mx, __shfl_xor(mx, 2, 64));
      mx = fmaxf(mx, __shfl_xor(mx, 4, 64));
      mx = fmaxf(mx, __shfl_xor(mx, 8, 64));
      const float mnew = fmaxf(m_r[r], mx);
      scl[r] = __expf(m_r[r] - mnew);
      m_r[r] = mnew;
      float rs = 0.f;
      #pragma unroll
      for (int ft = 0; ft < 4; ++ft) {
        const float pexp = __expf(sf[ft][r] - mnew);
        sf[ft][r] = pexp;
        rs += pexp;
      }
      rs += __shfl_xor(rs, 1, 64);
      rs += __shfl_xor(rs, 2, 64);
      rs += __shfl_xor(rs, 4, 64);
      rs += __shfl_xor(rs, 8, 64);
      l_r[r] = l_r[r] * scl[r] + rs;
    }
    // P store: element (q = l4*4+r, t = ft*16+l15); slot = ft*2 + (l15>>3),
    // swizzled slot' = slot ^ (q&7); in-slot elem offset (l15&7)
    #pragma unroll
    for (int ft = 0; ft < 4; ++ft)
      #pragma unroll
      for (int r = 0; r < 4; ++r) {
        const int q = l4 * 4 + r;
        const int sl = (ft * 2 + (l15 >> 3)) ^ (q & 7);
        Plds[wave][q * 64 + sl * 8 + (l15 & 7)] = (bf16)sf[ft][r];
      }
    #pragma unroll
    for (int fd = 0; fd < 8; ++fd)
      #pragma unroll
      for (int r = 0; r < 4; ++r) oacc[fd][r] *= scl[r];
    #pragma unroll
    for (int fd = 0; fd < 8; ++fd) {
      #pragma unroll
      for (int kt = 0; kt < 2; ++kt) {
        // P read: q = l15, logical slot kt*4+l4 -> phys ^ (q&7)
        bf16x8 pa = *(const bf16x8*)(&Plds[wave][l15 * 64 +
                        (((kt * 4 + l4) ^ (l15 & 7)) * 8)]);
        // V read: row = fd*16+l15, logical slot kt*4+l4 -> phys ^ (row&7)
        bf16x8 vb = *(const bf16x8*)(Vs[buf] + (fd * 16 + l15) * 64 +
                        (((kt * 4 + l4) ^ (l15 & 7)) * 8));
        oacc[fd] = __builtin_amdgcn_mfma_f32_16x16x32_bf16(pa, vb, oacc[fd], 0, 0, 0);
      }
    }
    __syncthreads();
  }
  #pragma unroll
  for (int fd = 0; fd < 8; ++fd) {
    #pragma unroll
    for (int r = 0; r < 4; ++r) {
      const long row = qb * 64 + wave * 16 + l4 * 4 + r;
      outb[row * 4096 + head * 128 + fd * 16 + l15] = (bf16)(oacc[fd][r] / l_r[r]);
    }
  }
}

// ---------------------------------------------------------------------------
extern "C" void kernel_launch(void* const* d_in, const int* in_sizes, int n_in,
                              void* d_out, int out_size, void* d_ws, size_t ws_size,
                              hipStream_t stream) {
  const float* X  = (const float*)d_in[0];
  const float* Wq = (const float*)d_in[1];
  const float* Wk = (const float*)d_in[2];
  const float* Wv = (const float*)d_in[3];
  const float* Wo = (const float*)d_in[4];
  const float* bo = (const float*)d_in[5];
  const float* g1 = (const float*)d_in[6];
  const float* g2 = (const float*)d_in[7];
  const float* W1 = (const float*)d_in[8];
  const float* W2 = (const float*)d_in[9];
  const float* W3 = (const float*)d_in[10];
  float* out = (float*)d_out;

  hipFuncSetAttribute((const void*)gemmd<256, 3>, hipFuncAttributeMaxDynamicSharedMemorySize, 131072);
  hipFuncSetAttribute((const void*)gemmd<256, 4>, hipFuncAttributeMaxDynamicSharedMemorySize, 131072);
  hipFuncSetAttribute((const void*)gemmd<128, 1>, hipFuncAttributeMaxDynamicSharedMemorySize, 98304);
  hipFuncSetAttribute((const void*)gemmd<128, 2>, hipFuncAttributeMaxDynamicSharedMemorySize, 98304);

  char* p = (char*)d_ws;
  auto alloc = [&](size_t bytes) {
    char* r = p;
    p += (bytes + 255) & ~(size_t)255;
    return r;
  };
  float* cosT = (float*)alloc(2048 * 64 * 4);
  float* sinT = (float*)alloc(2048 * 64 * 4);
  bf16* WqkvT = (bf16*)alloc(12288L * 4096 * 2);   // [12288][4096]; later g
  bf16* WoT  = (bf16*)alloc(4096L * 4096 * 2);
  bf16* W12T = (bf16*)alloc(22016L * 4096 * 2);    // interleaved [22016][4096]
  bf16* W3T  = (bf16*)alloc(4096L * 11008 * 2);
  bf16* qhB  = (bf16*)alloc(2048L * 4096 * 2);     // [32][2048][128]
  bf16* khB  = (bf16*)alloc(2048L * 4096 * 2);
  bf16* vtB  = (bf16*)alloc(2048L * 4096 * 2);     // [32][128][2048]
  bf16* hbuf = (bf16*)alloc(2048L * 4096 * 2);     // h, then attnb
  bf16* h2   = (bf16*)alloc(2048L * 4096 * 2);
  float* X2  = (float*)alloc(2048L * 4096 * 4);

  bf16* gsw = (bf16*)WqkvT;   // g [2048][11008] (WqkvT dead after QKV GEMM)
  bf16* attnb = hbuf;

  prep_kernel<<<49920, 256, 0, stream>>>(Wq, Wk, Wv, Wo, W1, W2, W3,
                                         WqkvT, WoT, W12T, W3T, cosT, sinT);

  rmsnorm_kernel<<<2048, 256, 0, stream>>>(X, g1, hbuf, 4096);

  // q,k,v = rope/reorder(h @ [Wq|Wk|Wv])  — drift-256, fused epilogue
  gemmd<256, 3><<<384, 512, 131072, stream>>>(hbuf, WqkvT, nullptr, nullptr, nullptr,
                                              cosT, sinT, qhB, khB, vtB,
                                              2048, 12288, 4096, 8);

  attn_kernel<<<dim3(32, 32), 256, 0, stream>>>(qhB, khB, vtB, attnb);

  // X2 = attn @ Wo + bo + X   (drift-128)
  gemmd<128, 1><<<256, 512, 98304, stream>>>(attnb, WoT, X2, bo, X,
                                             nullptr, nullptr, nullptr, nullptr, nullptr,
                                             2048, 4096, 4096, 16);

  rmsnorm_kernel<<<2048, 256, 0, stream>>>(X2, g2, h2, 4096);

  // g = silu(h2@W1) * (h2@W2)  — drift-256, fused SwiGLU epilogue
  gemmd<256, 4><<<688, 512, 131072, stream>>>(h2, W12T, gsw, nullptr, nullptr,
                                              nullptr, nullptr, nullptr, nullptr, nullptr,
                                              2048, 22016, 4096, 8);

  // out = g @ W3 + X2   (drift-128)
  gemmd<128, 2><<<256, 512, 98304, stream>>>(gsw, W3T, out, nullptr, X2,
                                             nullptr, nullptr, nullptr, nullptr, nullptr,
                                             2048, 4096, 11008, 16);
}

// Round 13
// 1220.727 us; speedup vs baseline: 1.1587x; 1.0708x over previous
//
#include <hip/hip_runtime.h>
#include <hip/hip_bf16.h>
#include <cstdint>
#include <cmath>

typedef __bf16 bf16;
typedef __attribute__((ext_vector_type(8))) __bf16 bf16x8;
typedef __attribute__((ext_vector_type(4))) __bf16 bf16x4;
typedef __attribute__((ext_vector_type(4))) float f32x4;

// async global->LDS, 16B per lane, dest = wave-uniform base (+ lane*16 by HW)
__device__ __forceinline__ void gload_lds16(const void* g, void* l) {
  __builtin_amdgcn_global_load_lds((__attribute__((address_space(1))) void*)g,
                                   (__attribute__((address_space(3))) void*)l,
                                   16, 0, 0);
}

// ---------------------------------------------------------------------------
// Drift GEMM (R11 best form): BM x 256 tile, BK=64, 8 waves (4M x 2N: wave =
// BM/4 rows x 128 cols), dbuf LDS, one __syncthreads per K-tile, full-tile
// prefetch front-loaded. C = A[M,K] @ Bt^T (Bt stored [N][ksd] bf16).
// ksd = row stride (elements); K = this block's K-extent (for split-K).
// EPI 1: f32 = acc+bias[col]+resid (Wo).
// EPI 3: QKV fused RoPE + head reorder.  EPI 4: fused SwiGLU.
// EPI 5: split-K bf16 partial -> q_out (split 0) / v_out (split 1).
// ---------------------------------------------------------------------------
template<int BM, int EPI>
__global__ __launch_bounds__(512, 2) void gemmd(
    const bf16* __restrict__ A, const bf16* __restrict__ Bt, void* __restrict__ Cv,
    const float* __restrict__ bias, const float* __restrict__ resid,
    const float* __restrict__ cosT, const float* __restrict__ sinT,
    bf16* __restrict__ q_out, bf16* __restrict__ k_out, bf16* __restrict__ v_out,
    int M, int N, int K, int ksd, int gm) {
  extern __shared__ char lds[];
  constexpr int ASZ = BM * 128;
  constexpr int BUFS = ASZ + 32768;
  constexpr int MF = BM / 64;
  constexpr int LA = BM / 64;

  const int tid = threadIdx.x;
  const int wave = tid >> 6, lane = tid & 63;
  const int wr = wave >> 1, wc = wave & 1;   // 4M x 2N wave grid
  const int l15 = lane & 15, l4 = lane >> 4;
  const int qq = gridDim.x >> 3;
  const int wgid = (blockIdx.x & 7) * qq + (blockIdx.x >> 3);
  const int tm = wgid % gm;
  int tq = wgid / gm;
  int split = 0;
  if (EPI == 5) { split = tq / (N >> 8); tq = tq % (N >> 8); }
  const int tn = tq;
  const long brow = (long)tm * BM, bcol = (long)tn * 256;
  const long koff = (long)split * K;
  const int NT = K >> 6;
  const bf16* Ab = A + brow * ksd + koff;
  const bf16* Bb = Bt + bcol * ksd + koff;

  f32x4 acc[MF][8];
  #pragma unroll
  for (int i = 0; i < MF; ++i)
    #pragma unroll
    for (int j = 0; j < 8; ++j) acc[i][j] = (f32x4){0.f, 0.f, 0.f, 0.f};

  bf16x8 a[MF][2], b[8][2];

  auto stage = [&](int T) {
    const long kofs = (long)T << 6;
    char* wb = lds + (T & 1) * BUFS;
    #pragma unroll
    for (int i = 0; i < LA; ++i) {
      const int slot = i * 512 + tid, r = slot >> 3, c0 = slot & 7;
      gload_lds16(Ab + (long)r * ksd + kofs + ((c0 ^ (r & 7)) << 3), wb + slot * 16);
    }
    #pragma unroll
    for (int i = 0; i < 4; ++i) {
      const int slot = i * 512 + tid, r = slot >> 3, c0 = slot & 7;
      gload_lds16(Bb + (long)r * ksd + kofs + ((c0 ^ (r & 7)) << 3), wb + ASZ + slot * 16);
    }
  };

  stage(0);
  __syncthreads();

  for (int g = 0; g < NT; ++g) {
    const int pg = (g & 1) * BUFS;
    if (g + 1 < NT) stage(g + 1);   // writes opposite buffer; fenced by barrier
    #pragma unroll
    for (int nf = 0; nf < 8; ++nf)
      #pragma unroll
      for (int ks = 0; ks < 2; ++ks) {
        const int r = wc * 128 + nf * 16 + l15;
        b[nf][ks] = *(const bf16x8*)(lds + pg + ASZ + r * 128 + (((ks * 4 + l4) ^ (r & 7)) << 4));
      }
    #pragma unroll
    for (int mf = 0; mf < MF; ++mf)
      #pragma unroll
      for (int ks = 0; ks < 2; ++ks) {
        const int r = wr * (BM / 4) + mf * 16 + l15;
        a[mf][ks] = *(const bf16x8*)(lds + pg + r * 128 + (((ks * 4 + l4) ^ (r & 7)) << 4));
      }
    #pragma unroll
    for (int ks = 0; ks < 2; ++ks)
      #pragma unroll
      for (int mf = 0; mf < MF; ++mf)
        #pragma unroll
        for (int nf = 0; nf < 8; ++nf)
          acc[mf][nf] = __builtin_amdgcn_mfma_f32_16x16x32_bf16(
              a[mf][ks], b[nf][ks], acc[mf][nf], 0, 0, 0);
    __syncthreads();
  }

  if (EPI == 1) {
    #pragma unroll
    for (int mf = 0; mf < MF; ++mf) {
      const long row0 = brow + wr * (BM / 4) + mf * 16 + l4 * 4;
      #pragma unroll
      for (int nf = 0; nf < 8; ++nf) {
        const long col = bcol + wc * 128 + nf * 16 + l15;
        #pragma unroll
        for (int rj = 0; rj < 4; ++rj) {
          const long idx = (row0 + rj) * N + col;
          ((float*)Cv)[idx] = acc[mf][nf][rj] + bias[col] + resid[idx];
        }
      }
    }
  } else if (EPI == 5) {
    bf16* dst = (split == 0 ? q_out : v_out);
    #pragma unroll
    for (int mf = 0; mf < MF; ++mf) {
      const long row0 = brow + wr * (BM / 4) + mf * 16 + l4 * 4;
      #pragma unroll
      for (int nf = 0; nf < 8; ++nf) {
        const long col = bcol + wc * 128 + nf * 16 + l15;
        #pragma unroll
        for (int rj = 0; rj < 4; ++rj)
          dst[(row0 + rj) * N + col] = (bf16)acc[mf][nf][rj];
      }
    }
  } else if (EPI == 3) {
    const int region = (int)(bcol >> 12);           // 0=Q, 1=K, 2=V
    const int hc = (int)(bcol & 4095) + wc * 128;
    const int h = hc >> 7;
    if (region < 2) {
      bf16* dh = (region == 0 ? q_out : k_out) + (long)h * 2048 * 128;
      #pragma unroll
      for (int mf = 0; mf < MF; ++mf) {
        #pragma unroll
        for (int rj = 0; rj < 4; ++rj) {
          const int s = (int)brow + wr * (BM / 4) + mf * 16 + l4 * 4 + rj;
          const float* cr = cosT + s * 64;
          const float* sr = sinT + s * 64;
          #pragma unroll
          for (int nfp = 0; nfp < 4; ++nfp) {
            const int d = nfp * 16 + l15;
            const float c = cr[d], sn = sr[d];
            const float x1 = acc[mf][nfp][rj], x2 = acc[mf][nfp + 4][rj];
            dh[(long)s * 128 + d]      = (bf16)(x1 * c - x2 * sn);
            dh[(long)s * 128 + d + 64] = (bf16)(x2 * c + x1 * sn);
          }
        }
      }
    } else {
      bf16* dh = v_out + (long)h * 128 * 2048;
      #pragma unroll
      for (int mf = 0; mf < MF; ++mf) {
        const int s0 = (int)brow + wr * (BM / 4) + mf * 16 + l4 * 4;
        #pragma unroll
        for (int nf = 0; nf < 8; ++nf) {
          const int d = nf * 16 + l15;
          bf16x4 v;
          #pragma unroll
          for (int rj = 0; rj < 4; ++rj) v[rj] = (bf16)acc[mf][nf][rj];
          *(bf16x4*)(dh + (long)d * 2048 + s0) = v;
        }
      }
    }
  } else if (EPI == 4) {
    #pragma unroll
    for (int mf = 0; mf < MF; ++mf) {
      #pragma unroll
      for (int rj = 0; rj < 4; ++rj) {
        const int s = (int)brow + wr * (BM / 4) + mf * 16 + l4 * 4 + rj;
        bf16* gr = (bf16*)Cv + (long)s * 11008;
        #pragma unroll
        for (int nfp = 0; nfp < 4; ++nfp) {
          const int col = (int)bcol + wc * 128 + nfp * 32 + l15;
          const int jj = ((col >> 5) << 4) + l15;
          const float x1 = acc[mf][2 * nfp][rj], x2 = acc[mf][2 * nfp + 1][rj];
          const float sg = x1 / (1.f + __expf(-x1));
          gr[jj] = (bf16)(sg * x2);
        }
      }
    }
  }
}

// ---------------------------------------------------------------------------
// Split-K combine: out = (f32)p0 + (f32)p1 + X2   (2048x4096)
// ---------------------------------------------------------------------------
__global__ __launch_bounds__(256) void combine_kernel(
    const bf16* __restrict__ p0, const bf16* __restrict__ p1,
    const float* __restrict__ X2, float* __restrict__ out) {
  const long i = ((long)blockIdx.x * 256 + threadIdx.x) * 8;
  bf16x8 a = *(const bf16x8*)(p0 + i);
  bf16x8 b = *(const bf16x8*)(p1 + i);
  #pragma unroll
  for (int j = 0; j < 8; ++j)
    out[i + j] = (float)a[j] + (float)b[j] + X2[i + j];
}

// ---------------------------------------------------------------------------
// Merged prep kernel (unchanged)
// ---------------------------------------------------------------------------
__device__ __forceinline__ void trans64(
    const float* __restrict__ in, bf16* __restrict__ out,
    int R, int C, int bx, int by, int ilv, int off) {
  __shared__ float t[64][65];
  const int lr = threadIdx.x >> 4;
  const int lc4 = (threadIdx.x & 15) * 4;
  #pragma unroll
  for (int i = 0; i < 4; ++i) {
    const int r = lr + i * 16;
    const float4 v = *(const float4*)(in + (long)(by * 64 + r) * C + bx * 64 + lc4);
    t[r][lc4] = v.x; t[r][lc4 + 1] = v.y; t[r][lc4 + 2] = v.z; t[r][lc4 + 3] = v.w;
  }
  __syncthreads();
  const int oc = threadIdx.x >> 4;
  const int or4 = (threadIdx.x & 15) * 4;
  #pragma unroll
  for (int i = 0; i < 4; ++i) {
    const int c = oc + i * 16;
    const int j = bx * 64 + c;
    const int rdst = ilv ? (((j >> 4) << 5) + off + (j & 15)) : j;
    bf16x4 v;
    #pragma unroll
    for (int k = 0; k < 4; ++k) v[k] = (bf16)t[or4 + k][c];
    *(bf16x4*)(out + (long)rdst * R + by * 64 + or4) = v;
  }
}

__global__ __launch_bounds__(256) void prep_kernel(
    const float* __restrict__ Wq, const float* __restrict__ Wk,
    const float* __restrict__ Wv, const float* __restrict__ Wo,
    const float* __restrict__ W1, const float* __restrict__ W2,
    const float* __restrict__ W3,
    bf16* __restrict__ WqkvT, bf16* __restrict__ WoT,
    bf16* __restrict__ W12T, bf16* __restrict__ W3T,
    float* __restrict__ cosT, float* __restrict__ sinT) {
  const int bid = blockIdx.x;
  if (bid < 16384) {
    const int seg = bid >> 12, idx = bid & 4095;
    const float* in = (seg == 0 ? Wq : seg == 1 ? Wk : seg == 2 ? Wv : Wo);
    bf16* out = (seg == 3 ? WoT : WqkvT + (long)seg * 4096 * 4096);
    trans64(in, out, 4096, 4096, idx & 63, idx >> 6, 0, 0);
  } else if (bid < 38400) {
    const int idx = bid - 16384;
    const int seg = idx / 11008, li = idx % 11008;
    trans64(seg ? W2 : W1, W12T, 4096, 11008, li % 172, li / 172, 1, seg * 16);
  } else if (bid < 49408) {
    const int idx = bid - 38400;
    trans64(W3, W3T, 11008, 4096, idx & 63, idx >> 6, 0, 0);
  } else {
    const int gidx = (bid - 49408) * 256 + threadIdx.x;
    const int i = gidx & 63, s = gidx >> 6;
    const float inv = powf(10000.f, -(float)i / 64.f);
    const float ang = (float)s * inv;
    cosT[gidx] = cosf(ang);
    sinT[gidx] = sinf(ang);
  }
}

// ---------------------------------------------------------------------------
// RMSNorm: one block per row of [2048][4096] f32 -> bf16
// ---------------------------------------------------------------------------
__global__ __launch_bounds__(256) void rmsnorm_kernel(
    const float* __restrict__ X, const float* __restrict__ gamma,
    bf16* __restrict__ out, int D) {
  const int row = blockIdx.x;
  const float* xr = X + (long)row * D;
  float ss = 0.f;
  for (int i = threadIdx.x * 4; i < D; i += 1024) {
    float4 v = *(const float4*)(xr + i);
    ss += v.x * v.x + v.y * v.y + v.z * v.z + v.w * v.w;
  }
  #pragma unroll
  for (int off = 32; off; off >>= 1) ss += __shfl_down(ss, off, 64);
  __shared__ float wsum[4];
  if ((threadIdx.x & 63) == 0) wsum[threadIdx.x >> 6] = ss;
  __syncthreads();
  const float tot = wsum[0] + wsum[1] + wsum[2] + wsum[3];
  const float scale = rsqrtf(1e-7f + tot / (float)D);
  bf16* orow = out + (long)row * D;
  for (int i = threadIdx.x * 4; i < D; i += 1024) {
    float4 v = *(const float4*)(xr + i);
    float4 g = *(const float4*)(gamma + i);
    orow[i]     = (bf16)(v.x * scale * g.x);
    orow[i + 1] = (bf16)(v.y * scale * g.y);
    orow[i + 2] = (bf16)(v.z * scale * g.z);
    orow[i + 3] = (bf16)(v.w * scale * g.w);
  }
}

// ---------------------------------------------------------------------------
// Flash attention, causal. Block=(qb,head), 4 waves x 16 q-rows. K/V dbuf.
// Conflict-swizzled LDS (R12): source-permuted gload + XOR'd reads.
// ---------------------------------------------------------------------------
__global__ __launch_bounds__(256) void attn_kernel(
    const bf16* __restrict__ qh, const bf16* __restrict__ kh,
    const bf16* __restrict__ vt, bf16* __restrict__ outb) {
  constexpr int S = 2048;
  const int qb = blockIdx.x, head = blockIdx.y;
  const int tid = threadIdx.x, wave = tid >> 6, lane = tid & 63;
  __shared__ bf16 Ks[2][64 * 128];
  __shared__ bf16 Vs[2][128 * 64];
  __shared__ bf16 Plds[4][16 * 64];
  const bf16* qhh = qh + (long)head * S * 128;
  const bf16* khh = kh + (long)head * S * 128;
  const bf16* vth = vt + (long)head * 128 * S;

  const int l15 = lane & 15, l4 = lane >> 4;
  const int qrow = qb * 64 + wave * 16 + l15;
  bf16x8 qf[4];
  #pragma unroll
  for (int kf = 0; kf < 4; ++kf)
    qf[kf] = *(const bf16x8*)(qhh + (long)qrow * 128 + kf * 32 + l4 * 8);

  auto stageKV = [&](int tb, int buf) {
    #pragma unroll
    for (int i = 0; i < 4; ++i) {
      const int c = wave + 4 * i;
      const int krlow = (c & 3) * 4 + l4;
      gload_lds16(khh + (long)(tb * 64 + c * 4 + l4) * 128 + ((l15 ^ krlow) * 8),
                  Ks[buf] + c * 512);
      gload_lds16(vth + (long)(c * 8 + (lane >> 3)) * S + tb * 64 +
                      (((lane & 7) ^ (lane >> 3)) * 8),
                  Vs[buf] + c * 512);
    }
  };

  float m_r[4], l_r[4];
  #pragma unroll
  for (int r = 0; r < 4; ++r) { m_r[r] = -INFINITY; l_r[r] = 0.f; }
  f32x4 oacc[8] = {};
  const float scale = 0.08838834764831845f;

  stageKV(0, 0);
  __syncthreads();

  for (int tb = 0; tb <= qb; ++tb) {
    const int buf = tb & 1;
    if (tb < qb) stageKV(tb + 1, buf ^ 1);

    f32x4 sf[4];
    #pragma unroll
    for (int ft = 0; ft < 4; ++ft) {
      f32x4 acn = {};
      #pragma unroll
      for (int kf = 0; kf < 4; ++kf) {
        bf16x8 kfr = *(const bf16x8*)(Ks[buf] + (ft * 16 + l15) * 128 +
                                      (((kf * 4 + l4) ^ l15) * 8));
        acn = __builtin_amdgcn_mfma_f32_16x16x32_bf16(qf[kf], kfr, acn, 0, 0, 0);
      }
      #pragma unroll
      for (int r = 0; r < 4; ++r) sf[ft][r] = acn[r] * scale;
    }
    if (tb == qb) {
      #pragma unroll
      for (int ft = 0; ft < 4; ++ft) {
        const int t_l = ft * 16 + l15;
        #pragma unroll
        for (int r = 0; r < 4; ++r)
          if (t_l > wave * 16 + l4 * 4 + r) sf[ft][r] = -INFINITY;
      }
    }
    float scl[4];
    #pragma unroll
    for (int r = 0; r < 4; ++r) {
      float mx = fmaxf(fmaxf(sf[0][r], sf[1][r]), fmaxf(sf[2][r], sf[3][r]));
      mx = fmaxf(mx, __shfl_xor(mx, 1, 64));
      mx = fmaxf(mx, __shfl_xor(mx, 2, 64));
      mx = fmaxf(mx, __shfl_xor(mx, 4, 64));
      mx = fmaxf(mx, __shfl_xor(mx, 8, 64));
      const float mnew = fmaxf(m_r[r], mx);
      scl[r] = __expf(m_r[r] - mnew);
      m_r[r] = mnew;
      float rs = 0.f;
      #pragma unroll
      for (int ft = 0; ft < 4; ++ft) {
        const float pexp = __expf(sf[ft][r] - mnew);
        sf[ft][r] = pexp;
        rs += pexp;
      }
      rs += __shfl_xor(rs, 1, 64);
      rs += __shfl_xor(rs, 2, 64);
      rs += __shfl_xor(rs, 4, 64);
      rs += __shfl_xor(rs, 8, 64);
      l_r[r] = l_r[r] * scl[r] + rs;
    }
    #pragma unroll
    for (int ft = 0; ft < 4; ++ft)
      #pragma unroll
      for (int r = 0; r < 4; ++r) {
        const int q = l4 * 4 + r;
        const int sl = (ft * 2 + (l15 >> 3)) ^ (q & 7);
        Plds[wave][q * 64 + sl * 8 + (l15 & 7)] = (bf16)sf[ft][r];
      }
    #pragma unroll
    for (int fd = 0; fd < 8; ++fd)
      #pragma unroll
      for (int r = 0; r < 4; ++r) oacc[fd][r] *= scl[r];
    #pragma unroll
    for (int fd = 0; fd < 8; ++fd) {
      #pragma unroll
      for (int kt = 0; kt < 2; ++kt) {
        bf16x8 pa = *(const bf16x8*)(&Plds[wave][l15 * 64 +
                        (((kt * 4 + l4) ^ (l15 & 7)) * 8)]);
        bf16x8 vb = *(const bf16x8*)(Vs[buf] + (fd * 16 + l15) * 64 +
                        (((kt * 4 + l4) ^ (l15 & 7)) * 8));
        oacc[fd] = __builtin_amdgcn_mfma_f32_16x16x32_bf16(pa, vb, oacc[fd], 0, 0, 0);
      }
    }
    __syncthreads();
  }
  #pragma unroll
  for (int fd = 0; fd < 8; ++fd) {
    #pragma unroll
    for (int r = 0; r < 4; ++r) {
      const long row = qb * 64 + wave * 16 + l4 * 4 + r;
      outb[row * 4096 + head * 128 + fd * 16 + l15] = (bf16)(oacc[fd][r] / l_r[r]);
    }
  }
}

// ---------------------------------------------------------------------------
extern "C" void kernel_launch(void* const* d_in, const int* in_sizes, int n_in,
                              void* d_out, int out_size, void* d_ws, size_t ws_size,
                              hipStream_t stream) {
  const float* X  = (const float*)d_in[0];
  const float* Wq = (const float*)d_in[1];
  const float* Wk = (const float*)d_in[2];
  const float* Wv = (const float*)d_in[3];
  const float* Wo = (const float*)d_in[4];
  const float* bo = (const float*)d_in[5];
  const float* g1 = (const float*)d_in[6];
  const float* g2 = (const float*)d_in[7];
  const float* W1 = (const float*)d_in[8];
  const float* W2 = (const float*)d_in[9];
  const float* W3 = (const float*)d_in[10];
  float* out = (float*)d_out;

  hipFuncSetAttribute((const void*)gemmd<256, 3>, hipFuncAttributeMaxDynamicSharedMemorySize, 131072);
  hipFuncSetAttribute((const void*)gemmd<256, 4>, hipFuncAttributeMaxDynamicSharedMemorySize, 131072);
  hipFuncSetAttribute((const void*)gemmd<256, 5>, hipFuncAttributeMaxDynamicSharedMemorySize, 131072);
  hipFuncSetAttribute((const void*)gemmd<128, 1>, hipFuncAttributeMaxDynamicSharedMemorySize, 98304);

  char* p = (char*)d_ws;
  auto alloc = [&](size_t bytes) {
    char* r = p;
    p += (bytes + 255) & ~(size_t)255;
    return r;
  };
  float* cosT = (float*)alloc(2048 * 64 * 4);
  float* sinT = (float*)alloc(2048 * 64 * 4);
  bf16* WqkvT = (bf16*)alloc(12288L * 4096 * 2);   // [12288][4096]; later g
  bf16* WoT  = (bf16*)alloc(4096L * 4096 * 2);
  bf16* W12T = (bf16*)alloc(22016L * 4096 * 2);    // interleaved [22016][4096]
  bf16* W3T  = (bf16*)alloc(4096L * 11008 * 2);
  bf16* qhB  = (bf16*)alloc(2048L * 4096 * 2);     // q heads; later P0
  bf16* khB  = (bf16*)alloc(2048L * 4096 * 2);     // k heads; later P1
  bf16* vtB  = (bf16*)alloc(2048L * 4096 * 2);     // v^T heads
  bf16* hbuf = (bf16*)alloc(2048L * 4096 * 2);     // h, then attnb
  bf16* h2   = (bf16*)alloc(2048L * 4096 * 2);
  float* X2  = (float*)alloc(2048L * 4096 * 4);

  bf16* gsw = (bf16*)WqkvT;   // g [2048][11008] (WqkvT dead after QKV GEMM)
  bf16* attnb = hbuf;
  bf16* P0 = qhB;             // split-K partials (q/k dead after attention)
  bf16* P1 = khB;

  prep_kernel<<<49920, 256, 0, stream>>>(Wq, Wk, Wv, Wo, W1, W2, W3,
                                         WqkvT, WoT, W12T, W3T, cosT, sinT);

  rmsnorm_kernel<<<2048, 256, 0, stream>>>(X, g1, hbuf, 4096);

  // q,k,v = rope/reorder(h @ [Wq|Wk|Wv])  — drift-256, fused epilogue
  gemmd<256, 3><<<384, 512, 131072, stream>>>(hbuf, WqkvT, nullptr, nullptr, nullptr,
                                              cosT, sinT, qhB, khB, vtB,
                                              2048, 12288, 4096, 4096, 8);

  attn_kernel<<<dim3(32, 32), 256, 0, stream>>>(qhB, khB, vtB, attnb);

  // X2 = attn @ Wo + bo + X   (drift-128)
  gemmd<128, 1><<<256, 512, 98304, stream>>>(attnb, WoT, X2, bo, X,
                                             nullptr, nullptr, nullptr, nullptr, nullptr,
                                             2048, 4096, 4096, 4096, 16);

  rmsnorm_kernel<<<2048, 256, 0, stream>>>(X2, g2, h2, 4096);

  // g = silu(h2@W1) * (h2@W2)  — drift-256, fused SwiGLU epilogue
  gemmd<256, 4><<<688, 512, 131072, stream>>>(h2, W12T, gsw, nullptr, nullptr,
                                              nullptr, nullptr, nullptr, nullptr, nullptr,
                                              2048, 22016, 4096, 4096, 8);

  // W3 split-K=2, BM=256 tiles: 8m x 16n x 2split = 256 blocks, 86 K-tiles ea.
  // split 0 -> P0 (q_out), split 1 -> P1 (v_out); K extent 5504, stride 11008.
  gemmd<256, 5><<<256, 512, 131072, stream>>>(gsw, W3T, nullptr, nullptr, nullptr,
                                              nullptr, nullptr, P0, nullptr, P1,
                                              2048, 4096, 5504, 11008, 8);

  // out = P0 + P1 + X2
  combine_kernel<<<4096, 256, 0, stream>>>(P0, P1, X2, out);
}

// Round 14
// 1190.093 us; speedup vs baseline: 1.1885x; 1.0257x over previous
//
#include <hip/hip_runtime.h>
#include <hip/hip_bf16.h>
#include <cstdint>
#include <cmath>

typedef __bf16 bf16;
typedef __attribute__((ext_vector_type(8))) __bf16 bf16x8;
typedef __attribute__((ext_vector_type(4))) __bf16 bf16x4;
typedef __attribute__((ext_vector_type(4))) float f32x4;

// async global->LDS, 16B per lane, dest = wave-uniform base (+ lane*16 by HW)
__device__ __forceinline__ void gload_lds16(const void* g, void* l) {
  __builtin_amdgcn_global_load_lds((__attribute__((address_space(1))) void*)g,
                                   (__attribute__((address_space(3))) void*)l,
                                   16, 0, 0);
}

// ---------------------------------------------------------------------------
// Drift GEMM (R11/R13 proven): 256 x 256 tile, BK=64, 8 waves (4M x 2N: wave
// = 64 rows x 128 cols), dbuf LDS, one __syncthreads per K-tile, full-tile
// prefetch front-loaded. C = A[M,K] @ Bt^T (Bt stored [N][ksd] bf16).
// ksd = row stride (elements); K = this block's K-extent (for split-K).
// EPI 3: QKV fused RoPE + head reorder.  EPI 4: fused SwiGLU (16-interleave).
// EPI 5: split-K bf16 partial -> q_out (split 0) / v_out (split 1).
// ---------------------------------------------------------------------------
template<int EPI>
__global__ __launch_bounds__(512, 2) void gemmd(
    const bf16* __restrict__ A, const bf16* __restrict__ Bt, void* __restrict__ Cv,
    const float* __restrict__ cosT, const float* __restrict__ sinT,
    bf16* __restrict__ q_out, bf16* __restrict__ k_out, bf16* __restrict__ v_out,
    int M, int N, int K, int ksd, int gm) {
  extern __shared__ char lds[];
  constexpr int BM = 256;
  constexpr int ASZ = BM * 128;
  constexpr int BUFS = ASZ + 32768;
  constexpr int MF = 4;

  const int tid = threadIdx.x;
  const int wave = tid >> 6, lane = tid & 63;
  const int wr = wave >> 1, wc = wave & 1;   // 4M x 2N wave grid
  const int l15 = lane & 15, l4 = lane >> 4;
  const int qq = gridDim.x >> 3;
  const int wgid = (blockIdx.x & 7) * qq + (blockIdx.x >> 3);
  const int tm = wgid % gm;
  int tq = wgid / gm;
  int split = 0;
  if (EPI == 5) { split = tq / (N >> 8); tq = tq % (N >> 8); }
  const int tn = tq;
  const long brow = (long)tm * BM, bcol = (long)tn * 256;
  const long koff = (long)split * K;
  const int NT = K >> 6;
  const bf16* Ab = A + brow * ksd + koff;
  const bf16* Bb = Bt + bcol * ksd + koff;

  f32x4 acc[MF][8];
  #pragma unroll
  for (int i = 0; i < MF; ++i)
    #pragma unroll
    for (int j = 0; j < 8; ++j) acc[i][j] = (f32x4){0.f, 0.f, 0.f, 0.f};

  bf16x8 a[MF][2], b[8][2];

  auto stage = [&](int T) {
    const long kofs = (long)T << 6;
    char* wb = lds + (T & 1) * BUFS;
    #pragma unroll
    for (int i = 0; i < 4; ++i) {
      const int slot = i * 512 + tid, r = slot >> 3, c0 = slot & 7;
      gload_lds16(Ab + (long)r * ksd + kofs + ((c0 ^ (r & 7)) << 3), wb + slot * 16);
    }
    #pragma unroll
    for (int i = 0; i < 4; ++i) {
      const int slot = i * 512 + tid, r = slot >> 3, c0 = slot & 7;
      gload_lds16(Bb + (long)r * ksd + kofs + ((c0 ^ (r & 7)) << 3), wb + ASZ + slot * 16);
    }
  };

  stage(0);
  __syncthreads();

  for (int g = 0; g < NT; ++g) {
    const int pg = (g & 1) * BUFS;
    if (g + 1 < NT) stage(g + 1);   // writes opposite buffer; fenced by barrier
    #pragma unroll
    for (int nf = 0; nf < 8; ++nf)
      #pragma unroll
      for (int ks = 0; ks < 2; ++ks) {
        const int r = wc * 128 + nf * 16 + l15;
        b[nf][ks] = *(const bf16x8*)(lds + pg + ASZ + r * 128 + (((ks * 4 + l4) ^ (r & 7)) << 4));
      }
    #pragma unroll
    for (int mf = 0; mf < MF; ++mf)
      #pragma unroll
      for (int ks = 0; ks < 2; ++ks) {
        const int r = wr * 64 + mf * 16 + l15;
        a[mf][ks] = *(const bf16x8*)(lds + pg + r * 128 + (((ks * 4 + l4) ^ (r & 7)) << 4));
      }
    #pragma unroll
    for (int ks = 0; ks < 2; ++ks)
      #pragma unroll
      for (int mf = 0; mf < MF; ++mf)
        #pragma unroll
        for (int nf = 0; nf < 8; ++nf)
          acc[mf][nf] = __builtin_amdgcn_mfma_f32_16x16x32_bf16(
              a[mf][ks], b[nf][ks], acc[mf][nf], 0, 0, 0);
    __syncthreads();
  }

  if (EPI == 5) {
    bf16* dst = (split == 0 ? q_out : v_out);
    #pragma unroll
    for (int mf = 0; mf < MF; ++mf) {
      const long row0 = brow + wr * 64 + mf * 16 + l4 * 4;
      #pragma unroll
      for (int nf = 0; nf < 8; ++nf) {
        const long col = bcol + wc * 128 + nf * 16 + l15;
        #pragma unroll
        for (int rj = 0; rj < 4; ++rj)
          dst[(row0 + rj) * N + col] = (bf16)acc[mf][nf][rj];
      }
    }
  } else if (EPI == 3) {
    const int region = (int)(bcol >> 12);           // 0=Q, 1=K, 2=V
    const int hc = (int)(bcol & 4095) + wc * 128;
    const int h = hc >> 7;
    if (region < 2) {
      bf16* dh = (region == 0 ? q_out : k_out) + (long)h * 2048 * 128;
      #pragma unroll
      for (int mf = 0; mf < MF; ++mf) {
        #pragma unroll
        for (int rj = 0; rj < 4; ++rj) {
          const int s = (int)brow + wr * 64 + mf * 16 + l4 * 4 + rj;
          const float* cr = cosT + s * 64;
          const float* sr = sinT + s * 64;
          #pragma unroll
          for (int nfp = 0; nfp < 4; ++nfp) {
            const int d = nfp * 16 + l15;
            const float c = cr[d], sn = sr[d];
            const float x1 = acc[mf][nfp][rj], x2 = acc[mf][nfp + 4][rj];
            dh[(long)s * 128 + d]      = (bf16)(x1 * c - x2 * sn);
            dh[(long)s * 128 + d + 64] = (bf16)(x2 * c + x1 * sn);
          }
        }
      }
    } else {
      bf16* dh = v_out + (long)h * 128 * 2048;
      #pragma unroll
      for (int mf = 0; mf < MF; ++mf) {
        const int s0 = (int)brow + wr * 64 + mf * 16 + l4 * 4;
        #pragma unroll
        for (int nf = 0; nf < 8; ++nf) {
          const int d = nf * 16 + l15;
          bf16x4 v;
          #pragma unroll
          for (int rj = 0; rj < 4; ++rj) v[rj] = (bf16)acc[mf][nf][rj];
          *(bf16x4*)(dh + (long)d * 2048 + s0) = v;
        }
      }
    }
  } else if (EPI == 4) {
    #pragma unroll
    for (int mf = 0; mf < MF; ++mf) {
      #pragma unroll
      for (int rj = 0; rj < 4; ++rj) {
        const int s = (int)brow + wr * 64 + mf * 16 + l4 * 4 + rj;
        bf16* gr = (bf16*)Cv + (long)s * 11008;
        #pragma unroll
        for (int nfp = 0; nfp < 4; ++nfp) {
          const int col = (int)bcol + wc * 128 + nfp * 32 + l15;
          const int jj = ((col >> 5) << 4) + l15;
          const float x1 = acc[mf][2 * nfp][rj], x2 = acc[mf][2 * nfp + 1][rj];
          const float sg = x1 / (1.f + __expf(-x1));
          gr[jj] = (bf16)(sg * x2);
        }
      }
    }
  }
}

// ---------------------------------------------------------------------------
// W3 split-K combine: out = (f32)p0 + (f32)p1 + X2   (2048x4096)
// ---------------------------------------------------------------------------
__global__ __launch_bounds__(256) void combine_kernel(
    const bf16* __restrict__ p0, const bf16* __restrict__ p1,
    const float* __restrict__ X2, float* __restrict__ out) {
  const long i = ((long)blockIdx.x * 256 + threadIdx.x) * 8;
  bf16x8 a = *(const bf16x8*)(p0 + i);
  bf16x8 b = *(const bf16x8*)(p1 + i);
  #pragma unroll
  for (int j = 0; j < 8; ++j)
    out[i + j] = (float)a[j] + (float)b[j] + X2[i + j];
}

// ---------------------------------------------------------------------------
// Wo split-K combine fused with rmsnorm2: one block per row.
// X2 = p0 + p1 + bo + X  (f32, kept for final residual)
// h2 = rmsnorm(X2, g2)   (bf16, feeds FF GEMM)
// ---------------------------------------------------------------------------
__global__ __launch_bounds__(256) void combine_wo_kernel(
    const bf16* __restrict__ p0, const bf16* __restrict__ p1,
    const float* __restrict__ bo, const float* __restrict__ X,
    const float* __restrict__ g2, float* __restrict__ X2,
    bf16* __restrict__ h2) {
  const int row = blockIdx.x;
  const long base = (long)row * 4096;
  float v[16];
  float ss = 0.f;
  #pragma unroll
  for (int c = 0; c < 2; ++c) {
    const int col = threadIdx.x * 8 + c * 2048;
    bf16x8 a = *(const bf16x8*)(p0 + base + col);
    bf16x8 b = *(const bf16x8*)(p1 + base + col);
    #pragma unroll
    for (int j = 0; j < 8; ++j) {
      const float val = (float)a[j] + (float)b[j] + bo[col + j] + X[base + col + j];
      v[c * 8 + j] = val;
      ss += val * val;
      X2[base + col + j] = val;
    }
  }
  #pragma unroll
  for (int off = 32; off; off >>= 1) ss += __shfl_down(ss, off, 64);
  __shared__ float wsum[4];
  if ((threadIdx.x & 63) == 0) wsum[threadIdx.x >> 6] = ss;
  __syncthreads();
  const float tot = wsum[0] + wsum[1] + wsum[2] + wsum[3];
  const float scale = rsqrtf(1e-7f + tot / 4096.f);
  #pragma unroll
  for (int c = 0; c < 2; ++c) {
    const int col = threadIdx.x * 8 + c * 2048;
    bf16x8 o;
    #pragma unroll
    for (int j = 0; j < 8; ++j)
      o[j] = (bf16)(v[c * 8 + j] * scale * g2[col + j]);
    *(bf16x8*)(h2 + base + col) = o;
  }
}

// ---------------------------------------------------------------------------
// Merged prep kernel: weight transposes + RoPE tables + rmsnorm1.
//  [0,4096)      Wq -> WqkvT     [4096,8192)   Wk    [8192,12288)  Wv
//  [12288,16384) Wo -> WoT       [16384,27392) W1    [27392,38400) W2
//  [38400,49408) W3 -> W3T       [49408,49920) rope tables
//  [49920,51968) rmsnorm1: h = rmsnorm(X, g1)  (one block per row)
// ---------------------------------------------------------------------------
__device__ __forceinline__ void trans64(
    const float* __restrict__ in, bf16* __restrict__ out,
    int R, int C, int bx, int by, int ilv, int off) {
  __shared__ float t[64][65];
  const int lr = threadIdx.x >> 4;
  const int lc4 = (threadIdx.x & 15) * 4;
  #pragma unroll
  for (int i = 0; i < 4; ++i) {
    const int r = lr + i * 16;
    const float4 v = *(const float4*)(in + (long)(by * 64 + r) * C + bx * 64 + lc4);
    t[r][lc4] = v.x; t[r][lc4 + 1] = v.y; t[r][lc4 + 2] = v.z; t[r][lc4 + 3] = v.w;
  }
  __syncthreads();
  const int oc = threadIdx.x >> 4;
  const int or4 = (threadIdx.x & 15) * 4;
  #pragma unroll
  for (int i = 0; i < 4; ++i) {
    const int c = oc + i * 16;
    const int j = bx * 64 + c;
    const int rdst = ilv ? (((j >> 4) << 5) + off + (j & 15)) : j;
    bf16x4 v;
    #pragma unroll
    for (int k = 0; k < 4; ++k) v[k] = (bf16)t[or4 + k][c];
    *(bf16x4*)(out + (long)rdst * R + by * 64 + or4) = v;
  }
}

__global__ __launch_bounds__(256) void prep_kernel(
    const float* __restrict__ Wq, const float* __restrict__ Wk,
    const float* __restrict__ Wv, const float* __restrict__ Wo,
    const float* __restrict__ W1, const float* __restrict__ W2,
    const float* __restrict__ W3, const float* __restrict__ X,
    const float* __restrict__ g1,
    bf16* __restrict__ WqkvT, bf16* __restrict__ WoT,
    bf16* __restrict__ W12T, bf16* __restrict__ W3T,
    float* __restrict__ cosT, float* __restrict__ sinT,
    bf16* __restrict__ hbuf) {
  const int bid = blockIdx.x;
  if (bid < 16384) {
    const int seg = bid >> 12, idx = bid & 4095;
    const float* in = (seg == 0 ? Wq : seg == 1 ? Wk : seg == 2 ? Wv : Wo);
    bf16* out = (seg == 3 ? WoT : WqkvT + (long)seg * 4096 * 4096);
    trans64(in, out, 4096, 4096, idx & 63, idx >> 6, 0, 0);
  } else if (bid < 38400) {
    const int idx = bid - 16384;
    const int seg = idx / 11008, li = idx % 11008;
    trans64(seg ? W2 : W1, W12T, 4096, 11008, li % 172, li / 172, 1, seg * 16);
  } else if (bid < 49408) {
    const int idx = bid - 38400;
    trans64(W3, W3T, 11008, 4096, idx & 63, idx >> 6, 0, 0);
  } else if (bid < 49920) {
    const int gidx = (bid - 49408) * 256 + threadIdx.x;
    const int i = gidx & 63, s = gidx >> 6;
    const float inv = powf(10000.f, -(float)i / 64.f);
    const float ang = (float)s * inv;
    cosT[gidx] = cosf(ang);
    sinT[gidx] = sinf(ang);
  } else {
    const int row = bid - 49920;
    const float* xr = X + (long)row * 4096;
    float ss = 0.f;
    for (int i = threadIdx.x * 4; i < 4096; i += 1024) {
      float4 v = *(const float4*)(xr + i);
      ss += v.x * v.x + v.y * v.y + v.z * v.z + v.w * v.w;
    }
    #pragma unroll
    for (int off = 32; off; off >>= 1) ss += __shfl_down(ss, off, 64);
    __shared__ float wsum[4];
    if ((threadIdx.x & 63) == 0) wsum[threadIdx.x >> 6] = ss;
    __syncthreads();
    const float tot = wsum[0] + wsum[1] + wsum[2] + wsum[3];
    const float scale = rsqrtf(1e-7f + tot / 4096.f);
    bf16* orow = hbuf + (long)row * 4096;
    for (int i = threadIdx.x * 4; i < 4096; i += 1024) {
      float4 v = *(const float4*)(xr + i);
      float4 g = *(const float4*)(g1 + i);
      orow[i]     = (bf16)(v.x * scale * g.x);
      orow[i + 1] = (bf16)(v.y * scale * g.y);
      orow[i + 2] = (bf16)(v.z * scale * g.z);
      orow[i + 3] = (bf16)(v.w * scale * g.w);
    }
  }
}

// ---------------------------------------------------------------------------
// Flash attention, causal. Block=(qb,head), 4 waves x 16 q-rows. K/V dbuf.
// Conflict-swizzled LDS (R12): source-permuted gload + XOR'd reads.
// ---------------------------------------------------------------------------
__global__ __launch_bounds__(256) void attn_kernel(
    const bf16* __restrict__ qh, const bf16* __restrict__ kh,
    const bf16* __restrict__ vt, bf16* __restrict__ outb) {
  constexpr int S = 2048;
  const int qb = blockIdx.x, head = blockIdx.y;
  const int tid = threadIdx.x, wave = tid >> 6, lane = tid & 63;
  __shared__ bf16 Ks[2][64 * 128];
  __shared__ bf16 Vs[2][128 * 64];
  __shared__ bf16 Plds[4][16 * 64];
  const bf16* qhh = qh + (long)head * S * 128;
  const bf16* khh = kh + (long)head * S * 128;
  const bf16* vth = vt + (long)head * 128 * S;

  const int l15 = lane & 15, l4 = lane >> 4;
  const int qrow = qb * 64 + wave * 16 + l15;
  bf16x8 qf[4];
  #pragma unroll
  for (int kf = 0; kf < 4; ++kf)
    qf[kf] = *(const bf16x8*)(qhh + (long)qrow * 128 + kf * 32 + l4 * 8);

  auto stageKV = [&](int tb, int buf) {
    #pragma unroll
    for (int i = 0; i < 4; ++i) {
      const int c = wave + 4 * i;
      const int krlow = (c & 3) * 4 + l4;
      gload_lds16(khh + (long)(tb * 64 + c * 4 + l4) * 128 + ((l15 ^ krlow) * 8),
                  Ks[buf] + c * 512);
      gload_lds16(vth + (long)(c * 8 + (lane >> 3)) * S + tb * 64 +
                      (((lane & 7) ^ (lane >> 3)) * 8),
                  Vs[buf] + c * 512);
    }
  };

  float m_r[4], l_r[4];
  #pragma unroll
  for (int r = 0; r < 4; ++r) { m_r[r] = -INFINITY; l_r[r] = 0.f; }
  f32x4 oacc[8] = {};
  const float scale = 0.08838834764831845f;

  stageKV(0, 0);
  __syncthreads();

  for (int tb = 0; tb <= qb; ++tb) {
    const int buf = tb & 1;
    if (tb < qb) stageKV(tb + 1, buf ^ 1);

    f32x4 sf[4];
    #pragma unroll
    for (int ft = 0; ft < 4; ++ft) {
      f32x4 acn = {};
      #pragma unroll
      for (int kf = 0; kf < 4; ++kf) {
        bf16x8 kfr = *(const bf16x8*)(Ks[buf] + (ft * 16 + l15) * 128 +
                                      (((kf * 4 + l4) ^ l15) * 8));
        acn = __builtin_amdgcn_mfma_f32_16x16x32_bf16(qf[kf], kfr, acn, 0, 0, 0);
      }
      #pragma unroll
      for (int r = 0; r < 4; ++r) sf[ft][r] = acn[r] * scale;
    }
    if (tb == qb) {
      #pragma unroll
      for (int ft = 0; ft < 4; ++ft) {
        const int t_l = ft * 16 + l15;
        #pragma unroll
        for (int r = 0; r < 4; ++r)
          if (t_l > wave * 16 + l4 * 4 + r) sf[ft][r] = -INFINITY;
      }
    }
    float scl[4];
    #pragma unroll
    for (int r = 0; r < 4; ++r) {
      float mx = fmaxf(fmaxf(sf[0][r], sf[1][r]), fmaxf(sf[2][r], sf[3][r]));
      mx = fmaxf(mx, __shfl_xor(mx, 1, 64));
      mx = fmaxf(mx, __shfl_xor(mx, 2, 64));
      mx = fmaxf(mx, __shfl_xor(mx, 4, 64));
      mx = fmaxf(mx, __shfl_xor(mx, 8, 64));
      const float mnew = fmaxf(m_r[r], mx);
      scl[r] = __expf(m_r[r] - mnew);
      m_r[r] = mnew;
      float rs = 0.f;
      #pragma unroll
      for (int ft = 0; ft < 4; ++ft) {
        const float pexp = __expf(sf[ft][r] - mnew);
        sf[ft][r] = pexp;
        rs += pexp;
      }
      rs += __shfl_xor(rs, 1, 64);
      rs += __shfl_xor(rs, 2, 64);
      rs += __shfl_xor(rs, 4, 64);
      rs += __shfl_xor(rs, 8, 64);
      l_r[r] = l_r[r] * scl[r] + rs;
    }
    #pragma unroll
    for (int ft = 0; ft < 4; ++ft)
      #pragma unroll
      for (int r = 0; r < 4; ++r) {
        const int q = l4 * 4 + r;
        const int sl = (ft * 2 + (l15 >> 3)) ^ (q & 7);
        Plds[wave][q * 64 + sl * 8 + (l15 & 7)] = (bf16)sf[ft][r];
      }
    #pragma unroll
    for (int fd = 0; fd < 8; ++fd)
      #pragma unroll
      for (int r = 0; r < 4; ++r) oacc[fd][r] *= scl[r];
    #pragma unroll
    for (int fd = 0; fd < 8; ++fd) {
      #pragma unroll
      for (int kt = 0; kt < 2; ++kt) {
        bf16x8 pa = *(const bf16x8*)(&Plds[wave][l15 * 64 +
                        (((kt * 4 + l4) ^ (l15 & 7)) * 8)]);
        bf16x8 vb = *(const bf16x8*)(Vs[buf] + (fd * 16 + l15) * 64 +
                        (((kt * 4 + l4) ^ (l15 & 7)) * 8));
        oacc[fd] = __builtin_amdgcn_mfma_f32_16x16x32_bf16(pa, vb, oacc[fd], 0, 0, 0);
      }
    }
    __syncthreads();
  }
  #pragma unroll
  for (int fd = 0; fd < 8; ++fd) {
    #pragma unroll
    for (int r = 0; r < 4; ++r) {
      const long row = qb * 64 + wave * 16 + l4 * 4 + r;
      outb[row * 4096 + head * 128 + fd * 16 + l15] = (bf16)(oacc[fd][r] / l_r[r]);
    }
  }
}

// ---------------------------------------------------------------------------
extern "C" void kernel_launch(void* const* d_in, const int* in_sizes, int n_in,
                              void* d_out, int out_size, void* d_ws, size_t ws_size,
                              hipStream_t stream) {
  const float* X  = (const float*)d_in[0];
  const float* Wq = (const float*)d_in[1];
  const float* Wk = (const float*)d_in[2];
  const float* Wv = (const float*)d_in[3];
  const float* Wo = (const float*)d_in[4];
  const float* bo = (const float*)d_in[5];
  const float* g1 = (const float*)d_in[6];
  const float* g2 = (const float*)d_in[7];
  const float* W1 = (const float*)d_in[8];
  const float* W2 = (const float*)d_in[9];
  const float* W3 = (const float*)d_in[10];
  float* out = (float*)d_out;

  hipFuncSetAttribute((const void*)gemmd<3>, hipFuncAttributeMaxDynamicSharedMemorySize, 131072);
  hipFuncSetAttribute((const void*)gemmd<4>, hipFuncAttributeMaxDynamicSharedMemorySize, 131072);
  hipFuncSetAttribute((const void*)gemmd<5>, hipFuncAttributeMaxDynamicSharedMemorySize, 131072);

  char* p = (char*)d_ws;
  auto alloc = [&](size_t bytes) {
    char* r = p;
    p += (bytes + 255) & ~(size_t)255;
    return r;
  };
  float* cosT = (float*)alloc(2048 * 64 * 4);
  float* sinT = (float*)alloc(2048 * 64 * 4);
  bf16* WqkvT = (bf16*)alloc(12288L * 4096 * 2);   // [12288][4096]; later g
  bf16* WoT  = (bf16*)alloc(4096L * 4096 * 2);
  bf16* W12T = (bf16*)alloc(22016L * 4096 * 2);    // interleaved [22016][4096]
  bf16* W3T  = (bf16*)alloc(4096L * 11008 * 2);
  bf16* qhB  = (bf16*)alloc(2048L * 4096 * 2);     // q heads; later P0
  bf16* khB  = (bf16*)alloc(2048L * 4096 * 2);     // k heads; later P1
  bf16* vtB  = (bf16*)alloc(2048L * 4096 * 2);     // v^T heads
  bf16* hbuf = (bf16*)alloc(2048L * 4096 * 2);     // h, then attnb
  bf16* h2   = (bf16*)alloc(2048L * 4096 * 2);
  float* X2  = (float*)alloc(2048L * 4096 * 4);

  bf16* gsw = (bf16*)WqkvT;   // g [2048][11008] (WqkvT dead after QKV GEMM)
  bf16* attnb = hbuf;
  bf16* P0 = qhB;             // split-K partials (q/k dead after attention)
  bf16* P1 = khB;

  // weight transposes + rope tables + rmsnorm1 (h) in one launch
  prep_kernel<<<51968, 256, 0, stream>>>(Wq, Wk, Wv, Wo, W1, W2, W3, X, g1,
                                         WqkvT, WoT, W12T, W3T, cosT, sinT, hbuf);

  // q,k,v = rope/reorder(h @ [Wq|Wk|Wv])  — drift-256, fused epilogue
  gemmd<3><<<384, 512, 131072, stream>>>(hbuf, WqkvT, nullptr,
                                         cosT, sinT, qhB, khB, vtB,
                                         2048, 12288, 4096, 4096, 8);

  attn_kernel<<<dim3(32, 32), 256, 0, stream>>>(qhB, khB, vtB, attnb);

  // Wo split-K=2, BM=256: 8m x 16n x 2split = 256 blocks, 32 K-tiles each.
  gemmd<5><<<256, 512, 131072, stream>>>(attnb, WoT, nullptr,
                                         nullptr, nullptr, P0, nullptr, P1,
                                         2048, 4096, 2048, 4096, 8);

  // X2 = P0+P1+bo+X ; h2 = rmsnorm(X2, g2)   (fused per-row combine)
  combine_wo_kernel<<<2048, 256, 0, stream>>>(P0, P1, bo, X, g2, X2, h2);

  // g = silu(h2@W1) * (h2@W2)  — drift-256, fused SwiGLU epilogue
  gemmd<4><<<688, 512, 131072, stream>>>(h2, W12T, gsw,
                                         nullptr, nullptr, nullptr, nullptr, nullptr,
                                         2048, 22016, 4096, 4096, 8);

  // W3 split-K=2, BM=256: 256 blocks, 86 K-tiles each.
  gemmd<5><<<256, 512, 131072, stream>>>(gsw, W3T, nullptr,
                                         nullptr, nullptr, P0, nullptr, P1,
                                         2048, 4096, 5504, 11008, 8);

  // out = P0 + P1 + X2
  combine_kernel<<<4096, 256, 0, stream>>>(P0, P1, X2, out);
}